// Round 16
// baseline (51.285 us; speedup 1.0000x reference)
//
#include <hip/hip_runtime.h>

typedef short s8v __attribute__((ext_vector_type(8)));
typedef float f4v __attribute__((ext_vector_type(4)));

#define NTOK 1024
#define CD 128
#define QSCALE 0.25506953149031838f  // 32^-0.5 * log2(e)

__device__ __forceinline__ ushort f2bf(float x) {
    union { float f; unsigned u; } v; v.f = x;
    unsigned u = v.u + 0x7fff + ((v.u >> 16) & 1);
    return (ushort)(u >> 16);
}
__device__ __forceinline__ float bf2f(ushort x) {
    union { unsigned u; float f; } v; v.u = ((unsigned)x) << 16;
    return v.f;
}
__device__ __forceinline__ void gl_lds16(const ushort* g, ushort* l) {
    __builtin_amdgcn_global_load_lds(
        (const __attribute__((address_space(1))) unsigned int*)(g),
        (__attribute__((address_space(3))) unsigned int*)(l), 16, 0, 0);
}
__device__ __forceinline__ unsigned cvt_pk_bf16(float lo, float hi) {
    unsigned r;
    asm("v_cvt_pk_bf16_f32 %0, %1, %2" : "=v"(r) : "v"(lo), "v"(hi));
    return r;
}

// ---------------- Kernel 0: transpose/convert x -> xt (swizzled bf16), prep weights ----
// swizzle convention: element (row, c) stored at row*128 + ((c>>3)^(row&7))*8 + (c&7)
__global__ __launch_bounds__(256) void k_pre(const float* __restrict__ x,
                                             const float* __restrict__ Wp,
                                             const float* __restrict__ Wo,
                                             ushort* __restrict__ xt,
                                             ushort* __restrict__ wpre) {
    const int t = threadIdx.x;
    const int bx = blockIdx.x;
    if (bx < 256) {
        __shared__ ushort tile[128 * 68];
        const int b = bx >> 4;
        const int n0 = (bx & 15) << 6;
        #pragma unroll
        for (int p = 0; p < 8; ++p) {
            const int c = p * 16 + (t >> 4);
            const int n4 = t & 15;
            const float4 v = *(const float4*)&x[(b * CD + c) * NTOK + n0 + n4 * 4];
            ushort4 o;
            o.x = f2bf(v.x); o.y = f2bf(v.y); o.z = f2bf(v.z); o.w = f2bf(v.w);
            *(ushort4*)&tile[c * 68 + n4 * 4] = o;
        }
        __syncthreads();
        #pragma unroll
        for (int p = 0; p < 4; ++p) {
            const int nl = t >> 2;
            const int g = (t & 3) + p * 4;
            s8v tmp;
            #pragma unroll
            for (int e = 0; e < 8; ++e) tmp[e] = (short)tile[(g * 8 + e) * 68 + nl];
            const int n = n0 + nl;
            *(s8v*)&xt[(b * NTOK + n) * CD + ((g ^ (nl & 7)) * 8)] = tmp;
        }
    } else {
        const int kind = bx - 256;   // 0=q,1=k,2=v,3=Wo
        ushort* dst = wpre + kind * (CD * CD);
        for (int e = t * 4; e < CD * CD; e += 1024) {
            const int f = e >> 7, c = e & 127;
            const float* src;
            if (kind == 3) src = &Wo[f * CD + c];
            else           src = &Wp[((f >> 5) * 96 + kind * 32 + (f & 31)) * CD + c];
            const float4 v = *(const float4*)src;
            ushort4 o;
            o.x = f2bf(v.x); o.y = f2bf(v.y); o.z = f2bf(v.z); o.w = f2bf(v.w);
            *(ushort4*)&dst[f * CD + (((c >> 3) ^ (f & 7)) * 8) + (c & 7)] = o;
        }
    }
}

// ---------------- Kernel 1: QKV projection, bf16 MFMA (R14 version) ----------------
// vtb is stored with PV-permuted columns: within each 32-token block, token j is
// stored at position m = ((j&15)>>2)*8 + (j&3) + ((j>>4)<<2)  (R8-proven map).
__global__ __launch_bounds__(256) void k_proj(const ushort* __restrict__ xt,
                                              const ushort* __restrict__ wpre,
                                              const float* __restrict__ bp,
                                              ushort* __restrict__ qb,
                                              ushort* __restrict__ kb,
                                              ushort* __restrict__ vtb) {
    __shared__ ushort Abuf[128 * 128];
    __shared__ ushort Bbuf[64 * 128];
    const int t = threadIdx.x;
    const int lane = t & 63;
    const int w = t >> 6;
    const int li = lane & 15;
    const int lg = lane >> 4;
    const int bx = blockIdx.x;
    const int kind = bx >> 8;
    const int idx = bx & 255;

    const ushort* Asrc;
    const ushort* Bsrc;
    if (kind < 2) {
        Asrc = xt + (idx >> 1) * 128 * CD;
        Bsrc = wpre + kind * (CD * CD) + (idx & 1) * 64 * CD;
    } else {
        Asrc = wpre + 2 * (CD * CD);
        Bsrc = xt + idx * 64 * CD;
    }
    {
        const ushort* ga = Asrc + w * 4096;
        ushort* la = Abuf + w * 4096;
        #pragma unroll
        for (int i = 0; i < 8; ++i) gl_lds16(ga + i * 512 + lane * 8, la + i * 512);
        const ushort* gb = Bsrc + w * 2048;
        ushort* lb = Bbuf + w * 2048;
        #pragma unroll
        for (int i = 0; i < 4; ++i) gl_lds16(gb + i * 512 + lane * 8, lb + i * 512);
    }
    __syncthreads();

    const f4v fz = {0.f, 0.f, 0.f, 0.f};
    f4v acc[2][4];
    #pragma unroll
    for (int mf = 0; mf < 2; ++mf)
        #pragma unroll
        for (int nf = 0; nf < 4; ++nf) acc[mf][nf] = fz;
    const int m_base = w * 32;
    #pragma unroll
    for (int kk = 0; kk < 4; ++kk) {
        s8v a[2], bb[4];
        #pragma unroll
        for (int mf = 0; mf < 2; ++mf) {
            const int row = m_base + mf * 16 + li;
            a[mf] = *(const s8v*)&Abuf[row * CD + (((kk * 4 + lg) ^ (row & 7)) * 8)];
        }
        #pragma unroll
        for (int nf = 0; nf < 4; ++nf) {
            const int row = nf * 16 + li;
            bb[nf] = *(const s8v*)&Bbuf[row * CD + (((kk * 4 + lg) ^ (row & 7)) * 8)];
        }
        #pragma unroll
        for (int mf = 0; mf < 2; ++mf)
            #pragma unroll
            for (int nf = 0; nf < 4; ++nf)
                acc[mf][nf] = __builtin_amdgcn_mfma_f32_16x16x32_bf16(a[mf], bb[nf], acc[mf][nf], 0, 0, 0);
    }

    if (kind < 2) {
        ushort* dst = (kind == 0) ? qb : kb;
        const int m0 = (idx >> 1) * 128;
        const int f0 = (idx & 1) * 64;
        #pragma unroll
        for (int mf = 0; mf < 2; ++mf)
            #pragma unroll
            for (int nf = 0; nf < 4; ++nf) {
                const int f = f0 + nf * 16 + li;
                const int o = (f >> 5) * 96 + kind * 32 + (f & 31);
                const float bias = bp[o];
                #pragma unroll
                for (int r = 0; r < 4; ++r) {
                    const int row = m0 + m_base + mf * 16 + lg * 4 + r;
                    float v = acc[mf][nf][r] + bias;
                    if (kind == 0) v *= QSCALE;
                    dst[row * CD + f] = f2bf(v);
                }
            }
    } else {
        const int n0g = idx * 64;
        const int b = n0g >> 10;
        const int nl0 = n0g & 1023;
        #pragma unroll
        for (int mf = 0; mf < 2; ++mf)
            #pragma unroll
            for (int r = 0; r < 4; ++r) {
                const int f = m_base + mf * 16 + lg * 4 + r;
                const int o = (f >> 5) * 96 + 64 + (f & 31);
                const float bias = bp[o];
                #pragma unroll
                for (int nf = 0; nf < 4; ++nf) {
                    const int n = nl0 + nf * 16 + li;
                    const int jl = n & 31;
                    const int np = (n & ~31) | (((jl & 15) >> 2) * 8 + (jl & 3) + ((jl >> 4) << 2));
                    vtb[(b * CD + f) * NTOK + np] = f2bf(acc[mf][nf][r] + bias);
                }
            }
    }
}

// ---------------- Kernel 2: fused MFMA attention (R14 pipeline + wave-phase stagger) ----
// Grid: (b=16, it=16, js=4). Block = 4 waves; wave w owns i-rows [it*64+w*16, +16).
// Pipeline: S(tt) one iter ahead of PV; packed-bf16 wv state; one barrier/iter.
// K 2-buf write-before-barrier; V 2-buf write-after-barrier. LDS 37888 B.
// NEW: wave-phase STAGGER — even waves run S-then-PV, odd waves PV-then-S (both
// clusters depend only on post-barrier state), so MFMA and LDS/VALU phases
// interleave across waves on the CU instead of colliding in lockstep.
__global__ __launch_bounds__(256) void k_attn(const ushort* __restrict__ qb,
                                              const ushort* __restrict__ kb,
                                              const ushort* __restrict__ vtb,
                                              ushort* __restrict__ res4) {
    __shared__ ushort kbuf[2][32 * 136];   // 2 x 8704 B
    __shared__ ushort vbuf[2][128 * 40];   // 2 x 10240 B
    const int t = threadIdx.x;
    const int lane = t & 63;
    const int w = t >> 6;
    const int b = blockIdx.x;
    const int it = blockIdx.y;
    const int js = blockIdx.z;
    const int i0 = it * 64 + w * 16;
    const int li = lane & 15;
    const int lg = lane >> 4;

    s8v qf[4];
    #pragma unroll
    for (int h = 0; h < 4; ++h)
        qf[h] = *(const s8v*)&qb[(b*NTOK + i0 + li)*CD + h*32 + lg*8];

    const f4v fz = {0.f, 0.f, 0.f, 0.f};
    f4v acc[4][2];
    #pragma unroll
    for (int h = 0; h < 4; ++h) { acc[h][0] = fz; acc[h][1] = fz; }

    const int j0 = js * 256;
    const ushort* kptr0 = &kb[(b*NTOK + j0 + (t>>4))*CD + (t&15)*8];
    const ushort* kptr1 = kptr0 + 16*CD;
    const ushort* vptr0 = &vtb[(b*CD + (t>>2))*NTOK + j0 + (t&3)*8];
    const ushort* vptr1 = vptr0 + 64*NTOK;
    const int kwo = (t>>4)*136 + (t&15)*8;
    const int vwo = (t>>2)*40 + (t&3)*8;

    // prologue: K(0),V(0) -> buf0; prefetch K(1),V(1); S(0); softmax+pack -> wv
    s8v k0 = *(const s8v*)kptr0;
    s8v k1 = *(const s8v*)kptr1;
    s8v v0 = *(const s8v*)vptr0;
    s8v v1 = *(const s8v*)vptr1;
    *(s8v*)&kbuf[0][kwo]          = k0;
    *(s8v*)&kbuf[0][kwo + 16*136] = k1;
    *(s8v*)&vbuf[0][vwo]          = v0;
    *(s8v*)&vbuf[0][vwo + 64*40]  = v1;
    k0 = *(const s8v*)(kptr0 + 32*CD);
    k1 = *(const s8v*)(kptr1 + 32*CD);
    v0 = *(const s8v*)(vptr0 + 32);
    v1 = *(const s8v*)(vptr1 + 32);
    __syncthreads();

    unsigned wv[4][4];
    {
        f4v sv[4][2];
        __builtin_amdgcn_s_setprio(1);
        #pragma unroll
        for (int h = 0; h < 4; ++h)
            #pragma unroll
            for (int jh = 0; jh < 2; ++jh) {
                s8v kf = *(const s8v*)&kbuf[0][(jh*16 + li)*136 + h*32 + lg*8];
                sv[h][jh] = __builtin_amdgcn_mfma_f32_16x16x32_bf16(kf, qf[h], fz, 0, 0, 0);
            }
        __builtin_amdgcn_s_setprio(0);
        #pragma unroll
        for (int jh = 0; jh < 2; ++jh)
            #pragma unroll
            for (int r = 0; r < 4; ++r) {
                float e0 = __builtin_amdgcn_exp2f(sv[0][jh][r]);
                float e1 = __builtin_amdgcn_exp2f(sv[1][jh][r]);
                float e2 = __builtin_amdgcn_exp2f(sv[2][jh][r]);
                float e3 = __builtin_amdgcn_exp2f(sv[3][jh][r]);
                float inv = __builtin_amdgcn_rcpf(e0 + e1 + e2 + e3);
                sv[0][jh][r] = e0 * inv;
                sv[1][jh][r] = e1 * inv;
                sv[2][jh][r] = e2 * inv;
                sv[3][jh][r] = e3 * inv;
            }
        #pragma unroll
        for (int h = 0; h < 4; ++h) {
            wv[h][0] = cvt_pk_bf16(sv[h][0][0], sv[h][0][1]);
            wv[h][1] = cvt_pk_bf16(sv[h][0][2], sv[h][0][3]);
            wv[h][2] = cvt_pk_bf16(sv[h][1][0], sv[h][1][1]);
            wv[h][3] = cvt_pk_bf16(sv[h][1][2], sv[h][1][3]);
        }
    }

    #pragma unroll
    for (int tt = 1; tt <= 8; ++tt) {
        // K stage-write tile tt (regs loaded last iter) BEFORE barrier
        if (tt <= 7) {
            ushort* kn = kbuf[tt & 1];
            *(s8v*)&kn[kwo]          = k0;
            *(s8v*)&kn[kwo + 16*136] = k1;
        }
        __syncthreads();
        // V stage-write tile tt AFTER barrier (consumed next iter; target held
        // tile tt-2, fully read before this barrier)
        if (tt <= 7) {
            ushort* vn = vbuf[tt & 1];
            *(s8v*)&vn[vwo]          = v0;
            *(s8v*)&vn[vwo + 64*40]  = v1;
        }
        // prefetch tile tt+1 from global (consumed next iter)
        if (tt <= 6) {
            k0 = *(const s8v*)(kptr0 + (tt+1)*32*CD);
            k1 = *(const s8v*)(kptr1 + (tt+1)*32*CD);
            v0 = *(const s8v*)(vptr0 + (tt+1)*32);
            v1 = *(const s8v*)(vptr1 + (tt+1)*32);
        }
        // Two independent post-barrier clusters, STAGGERED by wave parity:
        //   S(tt):      kbuf[tt&1] x qf -> sv   (MFMA + K ds_reads)
        //   PV(tt-1):   wv x vbuf[(tt-1)&1]     (MFMA + V ds_reads)
        f4v sv[4][2];
        const ushort* kc = kbuf[tt & 1];
        const ushort* vc = vbuf[(tt - 1) & 1];
        if ((w & 1) == 0) {
            // even wave: S first
            if (tt <= 7) {
                __builtin_amdgcn_s_setprio(1);
                #pragma unroll
                for (int h = 0; h < 4; ++h)
                    #pragma unroll
                    for (int jh = 0; jh < 2; ++jh) {
                        s8v kf = *(const s8v*)&kc[(jh*16 + li)*136 + h*32 + lg*8];
                        sv[h][jh] = __builtin_amdgcn_mfma_f32_16x16x32_bf16(kf, qf[h], fz, 0, 0, 0);
                    }
                __builtin_amdgcn_s_setprio(0);
            }
            #pragma unroll
            for (int h = 0; h < 4; ++h) {
                union { unsigned d[4]; s8v s; } av;
                av.d[0] = wv[h][0]; av.d[1] = wv[h][1];
                av.d[2] = wv[h][2]; av.d[3] = wv[h][3];
                s8v vf0 = *(const s8v*)&vc[(h*32 + li)*40 + lg*8];
                s8v vf1 = *(const s8v*)&vc[(h*32 + 16 + li)*40 + lg*8];
                __builtin_amdgcn_s_setprio(1);
                acc[h][0] = __builtin_amdgcn_mfma_f32_16x16x32_bf16(av.s, vf0, acc[h][0], 0, 0, 0);
                acc[h][1] = __builtin_amdgcn_mfma_f32_16x16x32_bf16(av.s, vf1, acc[h][1], 0, 0, 0);
                __builtin_amdgcn_s_setprio(0);
            }
        } else {
            // odd wave: PV first
            #pragma unroll
            for (int h = 0; h < 4; ++h) {
                union { unsigned d[4]; s8v s; } av;
                av.d[0] = wv[h][0]; av.d[1] = wv[h][1];
                av.d[2] = wv[h][2]; av.d[3] = wv[h][3];
                s8v vf0 = *(const s8v*)&vc[(h*32 + li)*40 + lg*8];
                s8v vf1 = *(const s8v*)&vc[(h*32 + 16 + li)*40 + lg*8];
                __builtin_amdgcn_s_setprio(1);
                acc[h][0] = __builtin_amdgcn_mfma_f32_16x16x32_bf16(av.s, vf0, acc[h][0], 0, 0, 0);
                acc[h][1] = __builtin_amdgcn_mfma_f32_16x16x32_bf16(av.s, vf1, acc[h][1], 0, 0, 0);
                __builtin_amdgcn_s_setprio(0);
            }
            if (tt <= 7) {
                __builtin_amdgcn_s_setprio(1);
                #pragma unroll
                for (int h = 0; h < 4; ++h)
                    #pragma unroll
                    for (int jh = 0; jh < 2; ++jh) {
                        s8v kf = *(const s8v*)&kc[(jh*16 + li)*136 + h*32 + lg*8];
                        sv[h][jh] = __builtin_amdgcn_mfma_f32_16x16x32_bf16(kf, qf[h], fz, 0, 0, 0);
                    }
                __builtin_amdgcn_s_setprio(0);
            }
        }
        // softmax(tt) + pack -> wv for next iteration
        if (tt <= 7) {
            #pragma unroll
            for (int jh = 0; jh < 2; ++jh)
                #pragma unroll
                for (int r = 0; r < 4; ++r) {
                    float e0 = __builtin_amdgcn_exp2f(sv[0][jh][r]);
                    float e1 = __builtin_amdgcn_exp2f(sv[1][jh][r]);
                    float e2 = __builtin_amdgcn_exp2f(sv[2][jh][r]);
                    float e3 = __builtin_amdgcn_exp2f(sv[3][jh][r]);
                    float inv = __builtin_amdgcn_rcpf(e0 + e1 + e2 + e3);
                    sv[0][jh][r] = e0 * inv;
                    sv[1][jh][r] = e1 * inv;
                    sv[2][jh][r] = e2 * inv;
                    sv[3][jh][r] = e3 * inv;
                }
            #pragma unroll
            for (int h = 0; h < 4; ++h) {
                wv[h][0] = cvt_pk_bf16(sv[h][0][0], sv[h][0][1]);
                wv[h][1] = cvt_pk_bf16(sv[h][0][2], sv[h][0][3]);
                wv[h][2] = cvt_pk_bf16(sv[h][1][0], sv[h][1][1]);
                wv[h][3] = cvt_pk_bf16(sv[h][1][2], sv[h][1][3]);
            }
        }
    }

    #pragma unroll
    for (int h = 0; h < 4; ++h)
        #pragma unroll
        for (int dh = 0; dh < 2; ++dh)
            #pragma unroll
            for (int r = 0; r < 4; ++r) {
                const int i = i0 + lg*4 + r;
                const int f = h*32 + dh*16 + li;
                res4[js*(16*NTOK*CD) + (b*NTOK + i)*CD + f] = f2bf(acc[h][dh][r]);
            }
}

// ---------------- Kernel 3: output projection + bias + residual, bf16 MFMA ----------------
__global__ __launch_bounds__(256) void k_out(const ushort* __restrict__ wpre,
                                             const ushort* __restrict__ res4,
                                             const float* __restrict__ bo,
                                             const float* __restrict__ x,
                                             float* __restrict__ out) {
    __shared__ ushort Abuf[128 * 128];
    __shared__ ushort Bbuf[64 * 128];
    const int t = threadIdx.x;
    const int lane = t & 63;
    const int w = t >> 6;
    const int li = lane & 15;
    const int lg = lane >> 4;
    const int idx = blockIdx.x;
    const int n0g = idx * 64;
    const int b = n0g >> 10;
    {
        const ushort* ga = wpre + 3 * (CD * CD) + w * 4096;
        ushort* la = Abuf + w * 4096;
        #pragma unroll
        for (int i = 0; i < 8; ++i) gl_lds16(ga + i * 512 + lane * 8, la + i * 512);
    }
    for (int u = t; u < 64 * 16; u += 256) {
        const int rl = u >> 4, g = u & 15;
        const ushort* p = &res4[(n0g + rl) * CD + g * 8];
        s8v p0 = *(const s8v*)(p);
        s8v p1 = *(const s8v*)(p + 16*NTOK*CD);
        s8v p2 = *(const s8v*)(p + 32*NTOK*CD);
        s8v p3 = *(const s8v*)(p + 48*NTOK*CD);
        s8v sm;
        #pragma unroll
        for (int e = 0; e < 8; ++e)
            sm[e] = (short)f2bf(bf2f((ushort)p0[e]) + bf2f((ushort)p1[e])
                              + bf2f((ushort)p2[e]) + bf2f((ushort)p3[e]));
        *(s8v*)&Bbuf[rl * CD + ((g ^ (rl & 7)) * 8)] = sm;
    }
    __syncthreads();

    const f4v fz = {0.f, 0.f, 0.f, 0.f};
    f4v acc[2][4];
    #pragma unroll
    for (int mf = 0; mf < 2; ++mf)
        #pragma unroll
        for (int nf = 0; nf < 4; ++nf) acc[mf][nf] = fz;
    const int m_base = w * 32;
    #pragma unroll
    for (int kk = 0; kk < 4; ++kk) {
        s8v a[2], bb[4];
        #pragma unroll
        for (int mf = 0; mf < 2; ++mf) {
            const int row = m_base + mf * 16 + li;
            a[mf] = *(const s8v*)&Abuf[row * CD + (((kk * 4 + lg) ^ (row & 7)) * 8)];
        }
        #pragma unroll
        for (int nf = 0; nf < 4; ++nf) {
            const int row = nf * 16 + li;
            bb[nf] = *(const s8v*)&Bbuf[row * CD + (((kk * 4 + lg) ^ (row & 7)) * 8)];
        }
        #pragma unroll
        for (int mf = 0; mf < 2; ++mf)
            #pragma unroll
            for (int nf = 0; nf < 4; ++nf)
                acc[mf][nf] = __builtin_amdgcn_mfma_f32_16x16x32_bf16(a[mf], bb[nf], acc[mf][nf], 0, 0, 0);
    }
    const int nl0 = n0g & 1023;
    #pragma unroll
    for (int mf = 0; mf < 2; ++mf)
        #pragma unroll
        for (int r = 0; r < 4; ++r) {
            const int o = m_base + mf * 16 + lg * 4 + r;
            const float bias = bo[o];
            #pragma unroll
            for (int nf = 0; nf < 4; ++nf) {
                const int n = nl0 + nf * 16 + li;
                const int gi = (b * CD + o) * NTOK + n;
                out[gi] = acc[mf][nf][r] + bias + x[gi];
            }
        }
}

extern "C" void kernel_launch(void* const* d_in, const int* in_sizes, int n_in,
                              void* d_out, int out_size, void* d_ws, size_t ws_size,
                              hipStream_t stream) {
    const float* x  = (const float*)d_in[0];
    const float* Wp = (const float*)d_in[1];
    const float* bp = (const float*)d_in[2];
    const float* Wo = (const float*)d_in[3];
    const float* bo = (const float*)d_in[4];
    float* out = (float*)d_out;
    ushort* xt   = (ushort*)d_ws;                 // 4 MB
    ushort* wpre = xt + 16*1024*128;              // 128 KB
    ushort* qbw  = wpre + 4*128*128;              // 4 MB
    ushort* kbw  = qbw + 16*1024*128;             // 4 MB
    ushort* vtb  = kbw + 16*1024*128;             // 4 MB (PV-permuted columns)
    ushort* res4 = vtb + 16*1024*128;             // 16.8 MB (4 partials)
    k_pre <<<260, 256, 0, stream>>>(x, Wp, Wo, xt, wpre);
    k_proj<<<768, 256, 0, stream>>>(xt, wpre, bp, qbw, kbw, vtb);
    k_attn<<<dim3(16, 16, 4), 256, 0, stream>>>(qbw, kbw, vtb, res4);
    k_out <<<256, 256, 0, stream>>>(wpre, res4, bo, x, out);
}

// Round 17
// 48.866 us; speedup vs baseline: 1.0495x; 1.0495x over previous
//
#include <hip/hip_runtime.h>

typedef short s8v __attribute__((ext_vector_type(8)));
typedef float f4v __attribute__((ext_vector_type(4)));

#define NTOK 1024
#define CD 128
#define QSCALE 0.25506953149031838f  // 32^-0.5 * log2(e)

__device__ __forceinline__ ushort f2bf(float x) {
    union { float f; unsigned u; } v; v.f = x;
    unsigned u = v.u + 0x7fff + ((v.u >> 16) & 1);
    return (ushort)(u >> 16);
}
__device__ __forceinline__ float bf2f(ushort x) {
    union { unsigned u; float f; } v; v.u = ((unsigned)x) << 16;
    return v.f;
}
__device__ __forceinline__ void gl_lds16(const ushort* g, ushort* l) {
    __builtin_amdgcn_global_load_lds(
        (const __attribute__((address_space(1))) unsigned int*)(g),
        (__attribute__((address_space(3))) unsigned int*)(l), 16, 0, 0);
}
__device__ __forceinline__ unsigned cvt_pk_bf16(float lo, float hi) {
    unsigned r;
    asm("v_cvt_pk_bf16_f32 %0, %1, %2" : "=v"(r) : "v"(lo), "v"(hi));
    return r;
}

// ---------------- Kernel 0: transpose/convert x -> xt (swizzled bf16), prep weights ----
// swizzle convention: element (row, c) stored at row*128 + ((c>>3)^(row&7))*8 + (c&7)
__global__ __launch_bounds__(256) void k_pre(const float* __restrict__ x,
                                             const float* __restrict__ Wp,
                                             const float* __restrict__ Wo,
                                             ushort* __restrict__ xt,
                                             ushort* __restrict__ wpre) {
    const int t = threadIdx.x;
    const int bx = blockIdx.x;
    if (bx < 256) {
        __shared__ ushort tile[128 * 68];
        const int b = bx >> 4;
        const int n0 = (bx & 15) << 6;
        #pragma unroll
        for (int p = 0; p < 8; ++p) {
            const int c = p * 16 + (t >> 4);
            const int n4 = t & 15;
            const float4 v = *(const float4*)&x[(b * CD + c) * NTOK + n0 + n4 * 4];
            ushort4 o;
            o.x = f2bf(v.x); o.y = f2bf(v.y); o.z = f2bf(v.z); o.w = f2bf(v.w);
            *(ushort4*)&tile[c * 68 + n4 * 4] = o;
        }
        __syncthreads();
        #pragma unroll
        for (int p = 0; p < 4; ++p) {
            const int nl = t >> 2;
            const int g = (t & 3) + p * 4;
            s8v tmp;
            #pragma unroll
            for (int e = 0; e < 8; ++e) tmp[e] = (short)tile[(g * 8 + e) * 68 + nl];
            const int n = n0 + nl;
            *(s8v*)&xt[(b * NTOK + n) * CD + ((g ^ (nl & 7)) * 8)] = tmp;
        }
    } else {
        const int kind = bx - 256;   // 0=q,1=k,2=v,3=Wo
        ushort* dst = wpre + kind * (CD * CD);
        for (int e = t * 4; e < CD * CD; e += 1024) {
            const int f = e >> 7, c = e & 127;
            const float* src;
            if (kind == 3) src = &Wo[f * CD + c];
            else           src = &Wp[((f >> 5) * 96 + kind * 32 + (f & 31)) * CD + c];
            const float4 v = *(const float4*)src;
            ushort4 o;
            o.x = f2bf(v.x); o.y = f2bf(v.y); o.z = f2bf(v.z); o.w = f2bf(v.w);
            *(ushort4*)&dst[f * CD + (((c >> 3) ^ (f & 7)) * 8) + (c & 7)] = o;
        }
    }
}

// ---------------- Kernel 1: QKV projection, bf16 MFMA (R14 version) ----------------
// vtb is stored with PV-permuted columns: within each 32-token block, token j is
// stored at position m = ((j&15)>>2)*8 + (j&3) + ((j>>4)<<2)  (R8-proven map).
__global__ __launch_bounds__(256) void k_proj(const ushort* __restrict__ xt,
                                              const ushort* __restrict__ wpre,
                                              const float* __restrict__ bp,
                                              ushort* __restrict__ qb,
                                              ushort* __restrict__ kb,
                                              ushort* __restrict__ vtb) {
    __shared__ ushort Abuf[128 * 128];
    __shared__ ushort Bbuf[64 * 128];
    const int t = threadIdx.x;
    const int lane = t & 63;
    const int w = t >> 6;
    const int li = lane & 15;
    const int lg = lane >> 4;
    const int bx = blockIdx.x;
    const int kind = bx >> 8;
    const int idx = bx & 255;

    const ushort* Asrc;
    const ushort* Bsrc;
    if (kind < 2) {
        Asrc = xt + (idx >> 1) * 128 * CD;
        Bsrc = wpre + kind * (CD * CD) + (idx & 1) * 64 * CD;
    } else {
        Asrc = wpre + 2 * (CD * CD);
        Bsrc = xt + idx * 64 * CD;
    }
    {
        const ushort* ga = Asrc + w * 4096;
        ushort* la = Abuf + w * 4096;
        #pragma unroll
        for (int i = 0; i < 8; ++i) gl_lds16(ga + i * 512 + lane * 8, la + i * 512);
        const ushort* gb = Bsrc + w * 2048;
        ushort* lb = Bbuf + w * 2048;
        #pragma unroll
        for (int i = 0; i < 4; ++i) gl_lds16(gb + i * 512 + lane * 8, lb + i * 512);
    }
    __syncthreads();

    const f4v fz = {0.f, 0.f, 0.f, 0.f};
    f4v acc[2][4];
    #pragma unroll
    for (int mf = 0; mf < 2; ++mf)
        #pragma unroll
        for (int nf = 0; nf < 4; ++nf) acc[mf][nf] = fz;
    const int m_base = w * 32;
    #pragma unroll
    for (int kk = 0; kk < 4; ++kk) {
        s8v a[2], bb[4];
        #pragma unroll
        for (int mf = 0; mf < 2; ++mf) {
            const int row = m_base + mf * 16 + li;
            a[mf] = *(const s8v*)&Abuf[row * CD + (((kk * 4 + lg) ^ (row & 7)) * 8)];
        }
        #pragma unroll
        for (int nf = 0; nf < 4; ++nf) {
            const int row = nf * 16 + li;
            bb[nf] = *(const s8v*)&Bbuf[row * CD + (((kk * 4 + lg) ^ (row & 7)) * 8)];
        }
        #pragma unroll
        for (int mf = 0; mf < 2; ++mf)
            #pragma unroll
            for (int nf = 0; nf < 4; ++nf)
                acc[mf][nf] = __builtin_amdgcn_mfma_f32_16x16x32_bf16(a[mf], bb[nf], acc[mf][nf], 0, 0, 0);
    }

    if (kind < 2) {
        ushort* dst = (kind == 0) ? qb : kb;
        const int m0 = (idx >> 1) * 128;
        const int f0 = (idx & 1) * 64;
        #pragma unroll
        for (int mf = 0; mf < 2; ++mf)
            #pragma unroll
            for (int nf = 0; nf < 4; ++nf) {
                const int f = f0 + nf * 16 + li;
                const int o = (f >> 5) * 96 + kind * 32 + (f & 31);
                const float bias = bp[o];
                #pragma unroll
                for (int r = 0; r < 4; ++r) {
                    const int row = m0 + m_base + mf * 16 + lg * 4 + r;
                    float v = acc[mf][nf][r] + bias;
                    if (kind == 0) v *= QSCALE;
                    dst[row * CD + f] = f2bf(v);
                }
            }
    } else {
        const int n0g = idx * 64;
        const int b = n0g >> 10;
        const int nl0 = n0g & 1023;
        #pragma unroll
        for (int mf = 0; mf < 2; ++mf)
            #pragma unroll
            for (int r = 0; r < 4; ++r) {
                const int f = m_base + mf * 16 + lg * 4 + r;
                const int o = (f >> 5) * 96 + 64 + (f & 31);
                const float bias = bp[o];
                #pragma unroll
                for (int nf = 0; nf < 4; ++nf) {
                    const int n = nl0 + nf * 16 + li;
                    const int jl = n & 31;
                    const int np = (n & ~31) | (((jl & 15) >> 2) * 8 + (jl & 3) + ((jl >> 4) << 2));
                    vtb[(b * CD + f) * NTOK + np] = f2bf(acc[mf][nf][r] + bias);
                }
            }
    }
}

// ---------------- Kernel 2: fused MFMA attention (R14 pipeline, K via global_load_lds) --
// Grid: (b=16, it=16, js=4). Block = 4 waves; wave w owns i-rows [it*64+w*16, +16).
// Pipeline: S(tt) one iter ahead of PV; packed-bf16 wv state; one barrier/iter.
// K: XOR-swizzled linear kbuf, staged by global_load_lds DMA (16B/lane, pre-swizzled
//    per-lane global source; m173 pattern). Element (row, g) stored at
//    row*128 + ((g ^ (row&7))*8). DMA for tile tt+1 issued after barrier tt, lands
//    by barrier tt+1's vmcnt drain. 2-buf: writes kbuf[(tt+1)&1] vs reads kbuf[tt&1].
// V: reg-staged, 2-buf, write-after-barrier (R14-proven). LDS = 36864 B.
__global__ __launch_bounds__(256) void k_attn(const ushort* __restrict__ qb,
                                              const ushort* __restrict__ kb,
                                              const ushort* __restrict__ vtb,
                                              ushort* __restrict__ res4) {
    __shared__ ushort kbuf[2][32 * 128];   // 2 x 8192 B, linear + XOR swizzle
    __shared__ ushort vbuf[2][128 * 40];   // 2 x 10240 B
    const int t = threadIdx.x;
    const int lane = t & 63;
    const int w = t >> 6;
    const int b = blockIdx.x;
    const int it = blockIdx.y;
    const int js = blockIdx.z;
    const int i0 = it * 64 + w * 16;
    const int li = lane & 15;
    const int lg = lane >> 4;

    s8v qf[4];
    #pragma unroll
    for (int h = 0; h < 4; ++h)
        qf[h] = *(const s8v*)&qb[(b*NTOK + i0 + li)*CD + h*32 + lg*8];

    const f4v fz = {0.f, 0.f, 0.f, 0.f};
    f4v acc[4][2];
    #pragma unroll
    for (int h = 0; h < 4; ++h) { acc[h][0] = fz; acc[h][1] = fz; }

    const int j0 = js * 256;
    // K DMA: wave w stages chunks c={2w, 2w+1}; chunk c = rows 4c..4c+3 (1 KB).
    // lane l in chunk c: row = 4c + (l>>4), slot = l&15, source col-group = slot^(row&7).
    const int kr0 = (w*2)*4 + (lane>>4);
    const int kr1 = (w*2+1)*4 + (lane>>4);
    const ushort* ksrc0 = &kb[(b*NTOK + j0 + kr0)*CD + (((lane&15) ^ (kr0&7))*8)];
    const ushort* ksrc1 = &kb[(b*NTOK + j0 + kr1)*CD + (((lane&15) ^ (kr1&7))*8)];
    // V staging (R14): rows (t>>2)+{0,64}, seg t&3
    const ushort* vptr0 = &vtb[(b*CD + (t>>2))*NTOK + j0 + (t&3)*8];
    const ushort* vptr1 = vptr0 + 64*NTOK;
    const int vwo = (t>>2)*40 + (t&3)*8;

    // prologue: DMA K(0)->kbuf[0]; V(0) regs->vbuf[0]; DMA K(1)->kbuf[1]; prefetch V(1)
    gl_lds16(ksrc0, &kbuf[0][w*1024]);
    gl_lds16(ksrc1, &kbuf[0][w*1024 + 512]);
    s8v v0 = *(const s8v*)vptr0;
    s8v v1 = *(const s8v*)vptr1;
    *(s8v*)&vbuf[0][vwo]          = v0;
    *(s8v*)&vbuf[0][vwo + 64*40]  = v1;
    gl_lds16(ksrc0 + 32*CD, &kbuf[1][w*1024]);
    gl_lds16(ksrc1 + 32*CD, &kbuf[1][w*1024 + 512]);
    v0 = *(const s8v*)(vptr0 + 32);
    v1 = *(const s8v*)(vptr1 + 32);
    __syncthreads();   // drains DMA (K0,K1 landed), seals V(0)

    unsigned wv[4][4];
    {
        f4v sv[4][2];
        __builtin_amdgcn_s_setprio(1);
        #pragma unroll
        for (int h = 0; h < 4; ++h)
            #pragma unroll
            for (int jh = 0; jh < 2; ++jh) {
                const int row = jh*16 + li;
                s8v kf = *(const s8v*)&kbuf[0][row*128 + (((h*4 + lg) ^ (li & 7))*8)];
                sv[h][jh] = __builtin_amdgcn_mfma_f32_16x16x32_bf16(kf, qf[h], fz, 0, 0, 0);
            }
        __builtin_amdgcn_s_setprio(0);
        #pragma unroll
        for (int jh = 0; jh < 2; ++jh)
            #pragma unroll
            for (int r = 0; r < 4; ++r) {
                float e0 = __builtin_amdgcn_exp2f(sv[0][jh][r]);
                float e1 = __builtin_amdgcn_exp2f(sv[1][jh][r]);
                float e2 = __builtin_amdgcn_exp2f(sv[2][jh][r]);
                float e3 = __builtin_amdgcn_exp2f(sv[3][jh][r]);
                float inv = __builtin_amdgcn_rcpf(e0 + e1 + e2 + e3);
                sv[0][jh][r] = e0 * inv;
                sv[1][jh][r] = e1 * inv;
                sv[2][jh][r] = e2 * inv;
                sv[3][jh][r] = e3 * inv;
            }
        #pragma unroll
        for (int h = 0; h < 4; ++h) {
            wv[h][0] = cvt_pk_bf16(sv[h][0][0], sv[h][0][1]);
            wv[h][1] = cvt_pk_bf16(sv[h][0][2], sv[h][0][3]);
            wv[h][2] = cvt_pk_bf16(sv[h][1][0], sv[h][1][1]);
            wv[h][3] = cvt_pk_bf16(sv[h][1][2], sv[h][1][3]);
        }
    }

    #pragma unroll
    for (int tt = 1; tt <= 8; ++tt) {
        __syncthreads();   // K(tt) DMA landed; V(tt-1) writes visible; tile tt-2 reads done
        // V stage-write tile tt AFTER barrier (consumed next iter)
        if (tt <= 7) {
            ushort* vn = vbuf[tt & 1];
            *(s8v*)&vn[vwo]          = v0;
            *(s8v*)&vn[vwo + 64*40]  = v1;
        }
        // issue K(tt+1) DMA (lands by barrier tt+1); overwrites tile tt-1 (reads sealed)
        if (tt <= 6) {
            gl_lds16(ksrc0 + (tt+1)*32*CD, &kbuf[(tt+1) & 1][w*1024]);
            gl_lds16(ksrc1 + (tt+1)*32*CD, &kbuf[(tt+1) & 1][w*1024 + 512]);
        }
        // prefetch V(tt+1) regs (consumed next iter)
        if (tt <= 6) {
            v0 = *(const s8v*)(vptr0 + (tt+1)*32);
            v1 = *(const s8v*)(vptr1 + (tt+1)*32);
        }
        // S(tt): consumed at end of this iteration (latency hidden by PV)
        f4v sv[4][2];
        if (tt <= 7) {
            const ushort* kc = kbuf[tt & 1];
            __builtin_amdgcn_s_setprio(1);
            #pragma unroll
            for (int h = 0; h < 4; ++h)
                #pragma unroll
                for (int jh = 0; jh < 2; ++jh) {
                    const int row = jh*16 + li;
                    s8v kf = *(const s8v*)&kc[row*128 + (((h*4 + lg) ^ (li & 7))*8)];
                    sv[h][jh] = __builtin_amdgcn_mfma_f32_16x16x32_bf16(kf, qf[h], fz, 0, 0, 0);
                }
            __builtin_amdgcn_s_setprio(0);
        }
        // PV(tt-1): A = packed wv from last iteration; V from vbuf[(tt-1)&1]
        {
            const ushort* vc = vbuf[(tt - 1) & 1];
            #pragma unroll
            for (int h = 0; h < 4; ++h) {
                union { unsigned d[4]; s8v s; } av;
                av.d[0] = wv[h][0]; av.d[1] = wv[h][1];
                av.d[2] = wv[h][2]; av.d[3] = wv[h][3];
                s8v vf0 = *(const s8v*)&vc[(h*32 + li)*40 + lg*8];
                s8v vf1 = *(const s8v*)&vc[(h*32 + 16 + li)*40 + lg*8];
                __builtin_amdgcn_s_setprio(1);
                acc[h][0] = __builtin_amdgcn_mfma_f32_16x16x32_bf16(av.s, vf0, acc[h][0], 0, 0, 0);
                acc[h][1] = __builtin_amdgcn_mfma_f32_16x16x32_bf16(av.s, vf1, acc[h][1], 0, 0, 0);
                __builtin_amdgcn_s_setprio(0);
            }
        }
        // softmax(tt) + pack -> wv for next iteration
        if (tt <= 7) {
            #pragma unroll
            for (int jh = 0; jh < 2; ++jh)
                #pragma unroll
                for (int r = 0; r < 4; ++r) {
                    float e0 = __builtin_amdgcn_exp2f(sv[0][jh][r]);
                    float e1 = __builtin_amdgcn_exp2f(sv[1][jh][r]);
                    float e2 = __builtin_amdgcn_exp2f(sv[2][jh][r]);
                    float e3 = __builtin_amdgcn_exp2f(sv[3][jh][r]);
                    float inv = __builtin_amdgcn_rcpf(e0 + e1 + e2 + e3);
                    sv[0][jh][r] = e0 * inv;
                    sv[1][jh][r] = e1 * inv;
                    sv[2][jh][r] = e2 * inv;
                    sv[3][jh][r] = e3 * inv;
                }
            #pragma unroll
            for (int h = 0; h < 4; ++h) {
                wv[h][0] = cvt_pk_bf16(sv[h][0][0], sv[h][0][1]);
                wv[h][1] = cvt_pk_bf16(sv[h][0][2], sv[h][0][3]);
                wv[h][2] = cvt_pk_bf16(sv[h][1][0], sv[h][1][1]);
                wv[h][3] = cvt_pk_bf16(sv[h][1][2], sv[h][1][3]);
            }
        }
    }

    #pragma unroll
    for (int h = 0; h < 4; ++h)
        #pragma unroll
        for (int dh = 0; dh < 2; ++dh)
            #pragma unroll
            for (int r = 0; r < 4; ++r) {
                const int i = i0 + lg*4 + r;
                const int f = h*32 + dh*16 + li;
                res4[js*(16*NTOK*CD) + (b*NTOK + i)*CD + f] = f2bf(acc[h][dh][r]);
            }
}

// ---------------- Kernel 3: output projection + bias + residual, bf16 MFMA ----------------
__global__ __launch_bounds__(256) void k_out(const ushort* __restrict__ wpre,
                                             const ushort* __restrict__ res4,
                                             const float* __restrict__ bo,
                                             const float* __restrict__ x,
                                             float* __restrict__ out) {
    __shared__ ushort Abuf[128 * 128];
    __shared__ ushort Bbuf[64 * 128];
    const int t = threadIdx.x;
    const int lane = t & 63;
    const int w = t >> 6;
    const int li = lane & 15;
    const int lg = lane >> 4;
    const int idx = blockIdx.x;
    const int n0g = idx * 64;
    const int b = n0g >> 10;
    {
        const ushort* ga = wpre + 3 * (CD * CD) + w * 4096;
        ushort* la = Abuf + w * 4096;
        #pragma unroll
        for (int i = 0; i < 8; ++i) gl_lds16(ga + i * 512 + lane * 8, la + i * 512);
    }
    for (int u = t; u < 64 * 16; u += 256) {
        const int rl = u >> 4, g = u & 15;
        const ushort* p = &res4[(n0g + rl) * CD + g * 8];
        s8v p0 = *(const s8v*)(p);
        s8v p1 = *(const s8v*)(p + 16*NTOK*CD);
        s8v p2 = *(const s8v*)(p + 32*NTOK*CD);
        s8v p3 = *(const s8v*)(p + 48*NTOK*CD);
        s8v sm;
        #pragma unroll
        for (int e = 0; e < 8; ++e)
            sm[e] = (short)f2bf(bf2f((ushort)p0[e]) + bf2f((ushort)p1[e])
                              + bf2f((ushort)p2[e]) + bf2f((ushort)p3[e]));
        *(s8v*)&Bbuf[rl * CD + ((g ^ (rl & 7)) * 8)] = sm;
    }
    __syncthreads();

    const f4v fz = {0.f, 0.f, 0.f, 0.f};
    f4v acc[2][4];
    #pragma unroll
    for (int mf = 0; mf < 2; ++mf)
        #pragma unroll
        for (int nf = 0; nf < 4; ++nf) acc[mf][nf] = fz;
    const int m_base = w * 32;
    #pragma unroll
    for (int kk = 0; kk < 4; ++kk) {
        s8v a[2], bb[4];
        #pragma unroll
        for (int mf = 0; mf < 2; ++mf) {
            const int row = m_base + mf * 16 + li;
            a[mf] = *(const s8v*)&Abuf[row * CD + (((kk * 4 + lg) ^ (row & 7)) * 8)];
        }
        #pragma unroll
        for (int nf = 0; nf < 4; ++nf) {
            const int row = nf * 16 + li;
            bb[nf] = *(const s8v*)&Bbuf[row * CD + (((kk * 4 + lg) ^ (row & 7)) * 8)];
        }
        #pragma unroll
        for (int mf = 0; mf < 2; ++mf)
            #pragma unroll
            for (int nf = 0; nf < 4; ++nf)
                acc[mf][nf] = __builtin_amdgcn_mfma_f32_16x16x32_bf16(a[mf], bb[nf], acc[mf][nf], 0, 0, 0);
    }
    const int nl0 = n0g & 1023;
    #pragma unroll
    for (int mf = 0; mf < 2; ++mf)
        #pragma unroll
        for (int r = 0; r < 4; ++r) {
            const int o = m_base + mf * 16 + lg * 4 + r;
            const float bias = bo[o];
            #pragma unroll
            for (int nf = 0; nf < 4; ++nf) {
                const int n = nl0 + nf * 16 + li;
                const int gi = (b * CD + o) * NTOK + n;
                out[gi] = acc[mf][nf][r] + bias + x[gi];
            }
        }
}

extern "C" void kernel_launch(void* const* d_in, const int* in_sizes, int n_in,
                              void* d_out, int out_size, void* d_ws, size_t ws_size,
                              hipStream_t stream) {
    const float* x  = (const float*)d_in[0];
    const float* Wp = (const float*)d_in[1];
    const float* bp = (const float*)d_in[2];
    const float* Wo = (const float*)d_in[3];
    const float* bo = (const float*)d_in[4];
    float* out = (float*)d_out;
    ushort* xt   = (ushort*)d_ws;                 // 4 MB
    ushort* wpre = xt + 16*1024*128;              // 128 KB
    ushort* qbw  = wpre + 4*128*128;              // 4 MB
    ushort* kbw  = qbw + 16*1024*128;             // 4 MB
    ushort* vtb  = kbw + 16*1024*128;             // 4 MB (PV-permuted columns)
    ushort* res4 = vtb + 16*1024*128;             // 16.8 MB (4 partials)
    k_pre <<<260, 256, 0, stream>>>(x, Wp, Wo, xt, wpre);
    k_proj<<<768, 256, 0, stream>>>(xt, wpre, bp, qbw, kbw, vtb);
    k_attn<<<dim3(16, 16, 4), 256, 0, stream>>>(qbw, kbw, vtb, res4);
    k_out <<<256, 256, 0, stream>>>(wpre, res4, bo, x, out);
}